// Round 14
// baseline (209.513 us; speedup 1.0000x reference)
//
#include <hip/hip_runtime.h>

#define NUM_PTS 1024
#define NBATCH 128
#define BT 256                       // 4 waves: w = dir + 2*qhalf
#define NJC 8                        // q-chunks per direction (128 pts each)
#define JCH 64                       // points per wave (half chunk)
#define R 16                         // rows per thread (64 lanes x 16 = all 1024)
#define CHAMF_SCALE (1.0f / 1024.0f)
#define KLD_SCALE   (-0.5f * 0.1f / 32.0f)

// ws floats:
//   [0, 2*WS_DIR)      row partials [2][NJC][NBATCH][NUM_PTS] = 8.4 MB
//   [WS_PART]          int cnt[128] (per-batch), cnt[128] = global  (memset 0)
//   [WS_PART + 256]    float bsum[128]  (written once before read)
#define WS_CHUNK (NBATCH * NUM_PTS)          // 131072
#define WS_DIR   (NJC * WS_CHUNK)            // 1048576
#define WS_PART  (2 * WS_DIR)                // 2097152 floats

// One fused kernel, plain launch (cooperative launch fails under graph
// capture — R12). 1024 blocks = (c,b), b = blockIdx&127 (the 8 blocks of a
// batch share a mod-8 dispatch class -> same XCD L2). Chamfer phase = R11
// verbatim. Completion: all threads __threadfence(), thread0 atomicAdd on
// cnt[b]; the 8th finisher reduces batch b in-block (128 KB, L2-local,
// overlapped with other blocks' compute), adds batch-b KLD, stores bsum[b],
// bumps cnt[128]; the 128th finisher sums bsum[0..127] and stores out[0]
// (exactly once -> no pre-zero of out needed).
__global__ __launch_bounds__(BT, 4) void fused_kernel(
    const float* __restrict__ recon_x,
    const float* __restrict__ x,
    const float* __restrict__ mu,
    const float* __restrict__ logvar,
    float* __restrict__ ws,
    float* __restrict__ out)
{
    const int b  = blockIdx.x & 127;
    const int c  = blockIdx.x >> 7;          // 0..7
    const int w  = threadIdx.x >> 6;
    const int lt = threadIdx.x & 63;
    const int dir  = w & 1;
    const int half = w >> 1;

    int* const cnt    = (int*)(ws + WS_PART);
    float* const bsum = ws + WS_PART + 256;

    __shared__ float sq[4][4][JCH];          // wave-private q planes, 4 KB
    __shared__ float comb[2][NUM_PTS + 64];  // stride-17 combine buffer, 8.5 KB
    __shared__ int   sflag;
    __shared__ float red[BT / 64];

    // --- stage this wave's 64-pt q sub-chunk (wave-private: no barrier)
    {
        const float* qsrc = (dir == 0 ? recon_x : x)
            + (size_t)b * NUM_PTS * 3 + (size_t)(c * 128 + half * JCH + lt) * 3;
        const float qx = qsrc[0], qy = qsrc[1], qz = qsrc[2];
        sq[w][0][lt] = qx;
        sq[w][1][lt] = qy;
        sq[w][2][lt] = qz;
        sq[w][3][lt] = fmaf(qx, qx, fmaf(qy, qy, qz * qz));
    }

    // --- own 16 contiguous rows: 12 coalesced float4 loads, keep -2*coord
    const float* rp = (dir == 0 ? x : recon_x) + (size_t)b * NUM_PTS * 3;
    float vx[R], vy[R], vz[R], m[R];
    {
        float buf[48];
        const float4* __restrict__ s4 = (const float4*)(rp + 48 * lt);
        float4* bp = (float4*)buf;
#pragma unroll
        for (int i = 0; i < 12; ++i) bp[i] = s4[i];
#pragma unroll
        for (int k = 0; k < R; ++k) {
            vx[k] = -2.0f * buf[3 * k + 0];
            vy[k] = -2.0f * buf[3 * k + 1];
            vz[k] = -2.0f * buf[3 * k + 2];
            m[k]  = 1e30f;
        }
    }

    // --- 16 groups x 4 qpts over this wave's sub-chunk
    const float4* __restrict__ qxp = (const float4*)sq[w][0];
    const float4* __restrict__ qyp = (const float4*)sq[w][1];
    const float4* __restrict__ qzp = (const float4*)sq[w][2];
    const float4* __restrict__ q2p = (const float4*)sq[w][3];
#pragma unroll 2
    for (int g = 0; g < JCH / 4; ++g) {
        const float4 qx = qxp[g];
        const float4 qy = qyp[g];
        const float4 qz = qzp[g];
        const float4 q2 = q2p[g];
#pragma unroll
        for (int r = 0; r < R; ++r) {
            const float d0 = fmaf(vx[r], qx.x, fmaf(vy[r], qy.x, fmaf(vz[r], qz.x, q2.x)));
            const float d1 = fmaf(vx[r], qx.y, fmaf(vy[r], qy.y, fmaf(vz[r], qz.y, q2.y)));
            m[r] = fminf(fminf(m[r], d0), d1);            // v_min3_f32
        }
#pragma unroll
        for (int r = 0; r < R; ++r) {
            const float d2 = fmaf(vx[r], qx.z, fmaf(vy[r], qy.z, fmaf(vz[r], qz.z, q2.z)));
            const float d3 = fmaf(vx[r], qx.w, fmaf(vy[r], qy.w, fmaf(vz[r], qz.w, q2.w)));
            m[r] = fminf(fminf(m[r], d2), d3);
        }
    }

    // --- combine q-halves (stride 17 => only free 2-way bank aliasing)
    if (half == 0) {
#pragma unroll
        for (int k = 0; k < R; ++k)
            comb[dir][17 * lt + k] = m[k];
    }
    __syncthreads();
    if (half == 1) {
        float4* dst = (float4*)(ws + (size_t)dir * WS_DIR + (size_t)c * WS_CHUNK
                                + b * NUM_PTS + 16 * lt);
#pragma unroll
        for (int k4 = 0; k4 < 4; ++k4) {
            float o[4];
#pragma unroll
            for (int i = 0; i < 4; ++i) {
                const int k = 4 * k4 + i;
                const float mm = fminf(m[k], comb[dir][17 * lt + k]);
                const float r2 = 0.25f * fmaf(vx[k], vx[k],
                                        fmaf(vy[k], vy[k], vz[k] * vz[k]));
                o[i] = r2 + mm;
            }
            dst[k4] = make_float4(o[0], o[1], o[2], o[3]);
        }
    }

    // ===== completion: 8th block of batch b reduces the batch =====
    __threadfence();                          // release own ws stores
    __syncthreads();
    if (threadIdx.x == 0) sflag = atomicAdd(&cnt[b], 1);
    __syncthreads();
    if (sflag != 7) return;                   // block-uniform

    __threadfence();                          // acquire other blocks' ws stores
    float v = 0.0f;
#pragma unroll
    for (int gsel = 0; gsel < 2; ++gsel) {
        const int grp  = threadIdx.x + BT * gsel;   // 0..511
        const int rdir = grp >> 8;
        const int rowg = grp & 255;                 // float4 group in dir
        const float4* p = (const float4*)(ws + (size_t)rdir * WS_DIR
                                          + (size_t)b * NUM_PTS) + rowg;
        float4 mn = p[0];
#pragma unroll
        for (int cc = 1; cc < NJC; ++cc) {
            const float4 q = p[cc * (WS_CHUNK / 4)];
            mn.x = fminf(mn.x, q.x);
            mn.y = fminf(mn.y, q.y);
            mn.z = fminf(mn.z, q.z);
            mn.w = fminf(mn.w, q.w);
        }
        v += mn.x + mn.y + mn.z + mn.w;
    }
    v *= CHAMF_SCALE;
    if (threadIdx.x < 32) {                   // batch-b KLD (32 latents)
        const int t = b * 32 + threadIdx.x;
        const float lv = logvar[t];
        const float mm = mu[t];
        v += (1.0f + lv - mm * mm - expf(lv)) * KLD_SCALE;
    }
    for (int off = 32; off > 0; off >>= 1)
        v += __shfl_down(v, off, 64);
    if ((threadIdx.x & 63) == 0) red[threadIdx.x >> 6] = v;
    __syncthreads();
    if (threadIdx.x == 0) {
        float s = red[0] + red[1] + red[2] + red[3];
        bsum[b] = s;
        __threadfence();                      // release bsum[b]
        sflag = atomicAdd(&cnt[128], 1);
    }
    __syncthreads();
    if (sflag != 127) return;                 // block-uniform

    // ===== 128th finisher: sum the 128 batch sums, store out[0] once =====
    __threadfence();                          // acquire all bsum
    float f = (threadIdx.x < 128) ? bsum[threadIdx.x] : 0.0f;
    for (int off = 32; off > 0; off >>= 1)
        f += __shfl_down(f, off, 64);
    if ((threadIdx.x & 63) == 0) red[threadIdx.x >> 6] = f;
    __syncthreads();
    if (threadIdx.x == 0)
        out[0] = red[0] + red[1] + red[2] + red[3];
}

extern "C" void kernel_launch(void* const* d_in, const int* in_sizes, int n_in,
                              void* d_out, int out_size, void* d_ws, size_t ws_size,
                              hipStream_t stream) {
    const float* recon_x = (const float*)d_in[0];
    const float* x       = (const float*)d_in[1];
    const float* mu      = (const float*)d_in[2];
    const float* logvar  = (const float*)d_in[3];
    float* out = (float*)d_out;
    float* ws  = (float*)d_ws;            // needs 8.4 MB + 2 KB

    // zero the completion counters (ws is re-poisoned to 0xAA every launch)
    (void)hipMemsetAsync(ws + WS_PART, 0, 1024, stream);

    fused_kernel<<<NBATCH * NJC, BT, 0, stream>>>(recon_x, x, mu, logvar, ws, out);
}

// Round 15
// 87.589 us; speedup vs baseline: 2.3920x; 2.3920x over previous
//
#include <hip/hip_runtime.h>

#define NUM_PTS 1024
#define NBATCH 128
#define BT 256                       // 4 waves: w = dir + 2*qhalf
#define RT 256
#define NJC 8                        // stored q-chunks per direction (128 pts each)
#define JCH 64                       // points per wave (half chunk)
#define R 16                         // rows per thread (64 lanes x 16 = all 1024)
#define CHAMF_SCALE (1.0f / 1024.0f)
#define KLD_SCALE   (-0.5f * 0.1f / 32.0f)

// ws: float [2][NJC][NBATCH][NUM_PTS] row partials = 8.4 MB.
#define WS_CHUNK (NBATCH * NUM_PTS)          // 131072
#define WS_DIR   (NJC * WS_CHUNK)            // 1048576

// R11 structure, two changes:
//  * __launch_bounds__(256,2): R11's (256,4) capped VGPR at 128 yet the
//    allocator settled at ~52-60 arch VGPRs + AGPR/scratch shuffling of the
//    64-float row state (R13/R10 counter evidence: VGPR_Count 52/60 with
//    2x WRITE_SIZE). Cap 256 lets vx/vy/vz/m live in arch VGPRs; grid
//    (1024 blocks) still gives 4 blocks/CU if allocation lands <=128.
//  * block 0 zeroes out[0] (plain store; stream order precedes reduce's
//    atomicAdds) -> the memset dispatch is deleted (3 -> 2 dispatches).
__global__ __launch_bounds__(BT, 2) void chamfer_part(
    const float* __restrict__ recon_x,
    const float* __restrict__ x,
    float* __restrict__ ws,
    float* __restrict__ out)
{
    const int b  = blockIdx.x & 127;
    const int c  = blockIdx.x >> 7;          // 0..7
    const int w  = threadIdx.x >> 6;
    const int lt = threadIdx.x & 63;
    const int dir  = w & 1;
    const int half = w >> 1;

    if (blockIdx.x == 0 && threadIdx.x == 0) out[0] = 0.0f;

    __shared__ float sq[4][4][JCH];          // wave-private q planes, 4 KB
    __shared__ float comb[2][NUM_PTS + 64];  // stride-17 combine buffer, 8.5 KB

    // --- stage this wave's 64-pt q sub-chunk (wave-private: no barrier)
    {
        const float* qsrc = (dir == 0 ? recon_x : x)
            + (size_t)b * NUM_PTS * 3 + (size_t)(c * 128 + half * JCH + lt) * 3;
        const float qx = qsrc[0], qy = qsrc[1], qz = qsrc[2];
        sq[w][0][lt] = qx;
        sq[w][1][lt] = qy;
        sq[w][2][lt] = qz;
        sq[w][3][lt] = fmaf(qx, qx, fmaf(qy, qy, qz * qz));
    }

    // --- own 16 contiguous rows: 12 coalesced float4 loads, keep -2*coord
    const float* rp = (dir == 0 ? x : recon_x) + (size_t)b * NUM_PTS * 3;
    float vx[R], vy[R], vz[R], m[R];
    {
        float buf[48];
        const float4* __restrict__ s4 = (const float4*)(rp + 48 * lt);
        float4* bp = (float4*)buf;
#pragma unroll
        for (int i = 0; i < 12; ++i) bp[i] = s4[i];
#pragma unroll
        for (int k = 0; k < R; ++k) {
            vx[k] = -2.0f * buf[3 * k + 0];
            vy[k] = -2.0f * buf[3 * k + 1];
            vz[k] = -2.0f * buf[3 * k + 2];
            m[k]  = 1e30f;
        }
    }

    // --- 16 groups x 4 qpts over this wave's sub-chunk
    const float4* __restrict__ qxp = (const float4*)sq[w][0];
    const float4* __restrict__ qyp = (const float4*)sq[w][1];
    const float4* __restrict__ qzp = (const float4*)sq[w][2];
    const float4* __restrict__ q2p = (const float4*)sq[w][3];
#pragma unroll 2
    for (int g = 0; g < JCH / 4; ++g) {
        const float4 qx = qxp[g];
        const float4 qy = qyp[g];
        const float4 qz = qzp[g];
        const float4 q2 = q2p[g];
#pragma unroll
        for (int r = 0; r < R; ++r) {
            const float d0 = fmaf(vx[r], qx.x, fmaf(vy[r], qy.x, fmaf(vz[r], qz.x, q2.x)));
            const float d1 = fmaf(vx[r], qx.y, fmaf(vy[r], qy.y, fmaf(vz[r], qz.y, q2.y)));
            m[r] = fminf(fminf(m[r], d0), d1);            // v_min3_f32
        }
#pragma unroll
        for (int r = 0; r < R; ++r) {
            const float d2 = fmaf(vx[r], qx.z, fmaf(vy[r], qy.z, fmaf(vz[r], qz.z, q2.z)));
            const float d3 = fmaf(vx[r], qx.w, fmaf(vy[r], qy.w, fmaf(vz[r], qz.w, q2.w)));
            m[r] = fminf(fminf(m[r], d2), d3);
        }
    }

    // --- combine q-halves (stride 17 => only free 2-way bank aliasing)
    if (half == 0) {
#pragma unroll
        for (int k = 0; k < R; ++k)
            comb[dir][17 * lt + k] = m[k];
    }
    __syncthreads();
    if (half == 1) {
        float4* dst = (float4*)(ws + (size_t)dir * WS_DIR + (size_t)c * WS_CHUNK
                                + b * NUM_PTS + 16 * lt);
#pragma unroll
        for (int k4 = 0; k4 < 4; ++k4) {
            float o[4];
#pragma unroll
            for (int i = 0; i < 4; ++i) {
                const int k = 4 * k4 + i;
                const float mm = fminf(m[k], comb[dir][17 * lt + k]);
                const float r2 = 0.25f * fmaf(vx[k], vx[k],
                                        fmaf(vy[k], vy[k], vz[k] * vz[k]));
                o[i] = r2 + mm;
            }
            dst[k4] = make_float4(o[0], o[1], o[2], o[3]);
        }
    }
}

// Fold 8 chunk partials per row (4 rows/thread via float4), sum, fold KLD.
// 256 blocks x 256 threads cover 2 x 128 x 1024 row slots.
__global__ __launch_bounds__(RT) void reduce_kernel(
    const float* __restrict__ ws,
    const float* __restrict__ mu,
    const float* __restrict__ logvar,
    float* __restrict__ out)
{
    const int gid  = blockIdx.x * RT + threadIdx.x;   // 0..65535
    const int base = gid * 4;
    const int dir  = base >> 17;
    const int rem  = base & 131071;                   // b*1024 + row

    const float4* p = (const float4*)(ws + (size_t)dir * WS_DIR + rem);
    float4 mn = p[0];
#pragma unroll
    for (int c = 1; c < NJC; ++c) {
        const float4 q = p[c * (WS_CHUNK / 4)];
        mn.x = fminf(mn.x, q.x);
        mn.y = fminf(mn.y, q.y);
        mn.z = fminf(mn.z, q.z);
        mn.w = fminf(mn.w, q.w);
    }
    float v = (mn.x + mn.y + mn.z + mn.w) * CHAMF_SCALE;

    if (blockIdx.x < 16) {                            // 16*256 = 4096 latents
        const int t = blockIdx.x * RT + threadIdx.x;
        const float lv = logvar[t];
        const float mm = mu[t];
        v += (1.0f + lv - mm * mm - expf(lv)) * KLD_SCALE;
    }

    for (int off = 32; off > 0; off >>= 1)
        v += __shfl_down(v, off, 64);

    __shared__ float red[RT / 64];
    const int lane = threadIdx.x & 63;
    const int wv   = threadIdx.x >> 6;
    if (lane == 0) red[wv] = v;
    __syncthreads();
    if (threadIdx.x == 0) {
        float sum = 0.f;
        for (int wq = 0; wq < RT / 64; ++wq) sum += red[wq];
        atomicAdd(out, sum);
    }
}

extern "C" void kernel_launch(void* const* d_in, const int* in_sizes, int n_in,
                              void* d_out, int out_size, void* d_ws, size_t ws_size,
                              hipStream_t stream) {
    const float* recon_x = (const float*)d_in[0];
    const float* x       = (const float*)d_in[1];
    const float* mu      = (const float*)d_in[2];
    const float* logvar  = (const float*)d_in[3];
    float* out = (float*)d_out;
    float* ws  = (float*)d_ws;            // needs 8.4 MB

    chamfer_part<<<NBATCH * NJC, BT, 0, stream>>>(recon_x, x, ws, out);
    reduce_kernel<<<256, RT, 0, stream>>>(ws, mu, logvar, out);
}